// Round 1
// baseline (1314.502 us; speedup 1.0000x reference)
//
#include <hip/hip_runtime.h>
#include <math.h>

#define IN_C  256
#define HID_C 128
#define OUT_C 64

// ---------------- edge dtype detection + normalization ----------------
// Reference creates int64 edge_index; harness docs say int32. Detect on
// device: if the first 64 values interpreted as int64 are all valid node
// ids, the buffer is int64 (int32 data would need every 2nd id == 0).
__global__ void detect_kernel(const void* edges, int E, int n_nodes, int* flag) {
    if (threadIdx.x == 0 && blockIdx.x == 0) {
        const long long* p = (const long long*)edges;
        int k = E < 64 ? E : 64;
        int is64 = 1;
        for (int i = 0; i < k; ++i) {
            long long v = p[i];
            if (v < 0 || v >= n_nodes) { is64 = 0; break; }
        }
        *flag = is64;
    }
}

__global__ void convert_edges(const void* edges, int E, const int* __restrict__ flag,
                              int* __restrict__ src32, int* __restrict__ dst32) {
    int i = blockIdx.x * blockDim.x + threadIdx.x;
    if (i >= E) return;
    if (*flag) {
        const long long* p = (const long long*)edges;
        src32[i] = (int)p[i];
        dst32[i] = (int)p[(size_t)E + i];
    } else {
        const int* p = (const int*)edges;
        src32[i] = p[i];
        dst32[i] = p[(size_t)E + i];
    }
}

// ---------------- degree / norm ----------------
__global__ void init_deg(float* deg, int n) {
    int i = blockIdx.x * blockDim.x + threadIdx.x;
    if (i < n) deg[i] = 1.0f;  // self-loop
}

__global__ void count_deg(const int* __restrict__ dst, float* deg, int E) {
    int e = blockIdx.x * blockDim.x + threadIdx.x;
    if (e < E) atomicAdd(&deg[dst[e]], 1.0f);
}

__global__ void make_dis(float* deg_dis, int n) {
    int i = blockIdx.x * blockDim.x + threadIdx.x;
    if (i < n) deg_dis[i] = rsqrtf(deg_dis[i]);  // deg >= 1 always
}

// ---------------- f32 tiled GEMM: C[M][TN] = A[M][K] @ B[K][TN] ----------------
// TM rows per block, full TN cols, 4x4 micro-tile per thread.
// THREADS must equal (TN/4)*(TM/4). M must be a multiple of TM.
template<int TM, int TN, int K, int KC, int THREADS>
__global__ __launch_bounds__(THREADS) void gemm_f32(
    const float* __restrict__ A, const float* __restrict__ B, float* __restrict__ C) {
    __shared__ float As[KC][TM + 1];   // +1 pad: conflict-free scalar-store/bcast-read
    __shared__ float Bs[KC][TN];
    const int tid = threadIdx.x;
    constexpr int TCN = TN / 4;
    const int tc = tid % TCN;
    const int tr = tid / TCN;
    const long long row0 = (long long)blockIdx.x * TM;
    float acc[4][4] = {};

    for (int k0 = 0; k0 < K; k0 += KC) {
        // stage A chunk transposed: As[kk][r]
        constexpr int A_LOADS = TM * KC / 4;
        for (int i = tid; i < A_LOADS; i += THREADS) {
            int r  = i / (KC / 4);
            int kq = i % (KC / 4);
            float4 a = *(const float4*)(A + (row0 + r) * K + k0 + kq * 4);
            As[kq * 4 + 0][r] = a.x;
            As[kq * 4 + 1][r] = a.y;
            As[kq * 4 + 2][r] = a.z;
            As[kq * 4 + 3][r] = a.w;
        }
        // stage B chunk: Bs[kk][c]
        constexpr int B_LOADS = KC * TN / 4;
        for (int i = tid; i < B_LOADS; i += THREADS) {
            int kk = i / TCN;
            int cq = i % TCN;
            *(float4*)(&Bs[kk][cq * 4]) = *(const float4*)(B + (long long)(k0 + kk) * TN + cq * 4);
        }
        __syncthreads();
        #pragma unroll 16
        for (int kk = 0; kk < KC; ++kk) {
            const float a0 = As[kk][tr * 4 + 0];
            const float a1 = As[kk][tr * 4 + 1];
            const float a2 = As[kk][tr * 4 + 2];
            const float a3 = As[kk][tr * 4 + 3];
            const float4 b = *(const float4*)(&Bs[kk][tc * 4]);
            acc[0][0] = fmaf(a0, b.x, acc[0][0]); acc[0][1] = fmaf(a0, b.y, acc[0][1]);
            acc[0][2] = fmaf(a0, b.z, acc[0][2]); acc[0][3] = fmaf(a0, b.w, acc[0][3]);
            acc[1][0] = fmaf(a1, b.x, acc[1][0]); acc[1][1] = fmaf(a1, b.y, acc[1][1]);
            acc[1][2] = fmaf(a1, b.z, acc[1][2]); acc[1][3] = fmaf(a1, b.w, acc[1][3]);
            acc[2][0] = fmaf(a2, b.x, acc[2][0]); acc[2][1] = fmaf(a2, b.y, acc[2][1]);
            acc[2][2] = fmaf(a2, b.z, acc[2][2]); acc[2][3] = fmaf(a2, b.w, acc[2][3]);
            acc[3][0] = fmaf(a3, b.x, acc[3][0]); acc[3][1] = fmaf(a3, b.y, acc[3][1]);
            acc[3][2] = fmaf(a3, b.z, acc[3][2]); acc[3][3] = fmaf(a3, b.w, acc[3][3]);
        }
        __syncthreads();
    }
    #pragma unroll
    for (int i = 0; i < 4; ++i) {
        float4 v = make_float4(acc[i][0], acc[i][1], acc[i][2], acc[i][3]);
        *(float4*)(C + (row0 + tr * 4 + i) * TN + tc * 4) = v;
    }
}

// ---------------- layer init (bias + self-loop term) ----------------
// agg[i][c] = b[c] + h[i][c]*dis[i]^2, vectorized float4. C must be mult of 4.
template<int C>
__global__ void init_layer(const float* __restrict__ h, const float* __restrict__ b,
                           const float* __restrict__ dis, float* __restrict__ agg, int n) {
    constexpr int CQ = C / 4;
    int idx = blockIdx.x * blockDim.x + threadIdx.x;   // over n*CQ
    if (idx >= n * CQ) return;
    int i  = idx / CQ;
    int cq = idx % CQ;
    float d  = dis[i];
    float d2 = d * d;
    float4 hv = ((const float4*)h)[idx];
    float4 bv = ((const float4*)b)[cq];
    float4 o;
    o.x = bv.x + hv.x * d2; o.y = bv.y + hv.y * d2;
    o.z = bv.z + hv.z * d2; o.w = bv.w + hv.w * d2;
    ((float4*)agg)[idx] = o;
}

// ---------------- edge scatter: agg[dst] += h[src]*dis[src]*dis[dst] ----------------
// C channels per edge; EPB edges per 256-thread block (EPB*C == 256).
template<int C, int EPB>
__global__ void scatter_edges(const float* __restrict__ h, const int* __restrict__ src,
                              const int* __restrict__ dst, const float* __restrict__ dis,
                              float* __restrict__ agg, int E) {
    int e = blockIdx.x * EPB + threadIdx.x / C;
    int c = threadIdx.x % C;
    if (e >= E) return;
    int s = src[e], d = dst[e];
    float norm = dis[s] * dis[d];
    atomicAdd(&agg[(size_t)d * C + c], h[(size_t)s * C + c] * norm);
}

extern "C" void kernel_launch(void* const* d_in, const int* in_sizes, int n_in,
                              void* d_out, int out_size, void* d_ws, size_t ws_size,
                              hipStream_t stream) {
    const float* x     = (const float*)d_in[0];
    const void*  edges = d_in[1];
    const float* W1    = (const float*)d_in[2];
    const float* b1    = (const float*)d_in[3];
    const float* W2    = (const float*)d_in[4];
    const float* b2    = (const float*)d_in[5];
    float* out = (float*)d_out;

    const int n = in_sizes[0] / IN_C;      // 100000
    const int E = in_sizes[1] / 2;         // 1600000

    // ---- workspace carve-up (all 256B-aligned) ----
    char* ws = (char*)d_ws;
    size_t off = 0;
    int* flag = (int*)(ws + off);          off += 256;
    int* src32 = (int*)(ws + off);         off += (size_t)E * 4;
    int* dst32 = (int*)(ws + off);         off += (size_t)E * 4;
    float* dis = (float*)(ws + off);       off += (((size_t)n * 4 + 255) / 256) * 256;
    float* h   = (float*)(ws + off);       off += (size_t)n * HID_C * 4;   // reused for h2
    float* agg = (float*)(ws + off);       off += (size_t)n * HID_C * 4;
    // total ~116 MB

    // 1. edge dtype normalize
    detect_kernel<<<1, 64, 0, stream>>>(edges, E, n, flag);
    convert_edges<<<(E + 255) / 256, 256, 0, stream>>>(edges, E, flag, src32, dst32);

    // 2. degree -> dis = deg^-1/2 (self-loop included)
    init_deg<<<(n + 255) / 256, 256, 0, stream>>>(dis, n);
    count_deg<<<(E + 255) / 256, 256, 0, stream>>>(dst32, dis, E);
    make_dis<<<(n + 255) / 256, 256, 0, stream>>>(dis, n);

    // 3. layer 1: h = x @ W1   (n divisible by 32)
    gemm_f32<32, HID_C, IN_C, 64, 256><<<n / 32, 256, 0, stream>>>(x, W1, h);
    // agg = b1 + h*dis^2 (self-loop) ...
    init_layer<HID_C><<<(n * (HID_C / 4) + 255) / 256, 256, 0, stream>>>(h, b1, dis, agg, n);
    // ... += sum_edges h[src]*norm
    scatter_edges<HID_C, 2><<<(E + 1) / 2, 256, 0, stream>>>(h, src32, dst32, dis, agg, E);

    // 4. layer 2: h2 = agg @ W2 (h buffer reused as h2)
    gemm_f32<32, OUT_C, HID_C, 64, 128><<<n / 32, 128, 0, stream>>>(agg, W2, h);
    init_layer<OUT_C><<<(n * (OUT_C / 4) + 255) / 256, 256, 0, stream>>>(h, b2, dis, out, n);
    scatter_edges<OUT_C, 4><<<(E + 3) / 4, 256, 0, stream>>>(h, src32, dst32, dis, out, E);
}

// Round 2
// 595.295 us; speedup vs baseline: 2.2082x; 2.2082x over previous
//
#include <hip/hip_runtime.h>
#include <math.h>

#define IN_C  256
#define HID_C 128
#define OUT_C 64

// ---------------- edge dtype detection ----------------
// Reference creates int64 edge_index; harness docs say int32. Detect on
// device: if the first 64 values interpreted as int64 are all valid node
// ids, the buffer is int64 (int32 data would need every 2nd id == 0).
__global__ void detect_kernel(const void* edges, int E, int n_nodes, int* flag) {
    if (threadIdx.x == 0 && blockIdx.x == 0) {
        const long long* p = (const long long*)edges;
        int k = E < 64 ? E : 64;
        int is64 = 1;
        for (int i = 0; i < k; ++i) {
            long long v = p[i];
            if (v < 0 || v >= n_nodes) { is64 = 0; break; }
        }
        *flag = is64;
    }
}

__device__ __forceinline__ int load_edge(const void* edges, size_t idx, int is64) {
    return is64 ? (int)((const long long*)edges)[idx] : ((const int*)edges)[idx];
}

// ---------------- degree / norm ----------------
__global__ void zero_counts(int* counts, int n) {
    int i = blockIdx.x * blockDim.x + threadIdx.x;
    if (i < n) counts[i] = 0;
}

__global__ void count_deg(const void* edges, const int* __restrict__ flag, int* counts, int E) {
    int e = blockIdx.x * blockDim.x + threadIdx.x;
    if (e < E) atomicAdd(&counts[load_edge(edges, (size_t)E + e, *flag)], 1);
}

__global__ void make_dis(const int* __restrict__ counts, float* dis, int n) {
    int i = blockIdx.x * blockDim.x + threadIdx.x;
    if (i < n) dis[i] = rsqrtf((float)counts[i] + 1.0f);  // +1 self-loop, deg >= 1
}

// ---------------- exclusive scan (3 kernels) ----------------
__global__ void scan_block(const int* __restrict__ counts, int* __restrict__ excl,
                           int* __restrict__ blockSums, int n) {
    __shared__ int tmp[256];
    int i = blockIdx.x * 256 + threadIdx.x;
    int v = (i < n) ? counts[i] : 0;
    tmp[threadIdx.x] = v;
    __syncthreads();
    for (int off = 1; off < 256; off <<= 1) {
        int t = (threadIdx.x >= off) ? tmp[threadIdx.x - off] : 0;
        __syncthreads();
        if (threadIdx.x >= off) tmp[threadIdx.x] += t;
        __syncthreads();
    }
    if (i < n) excl[i] = tmp[threadIdx.x] - v;
    if (threadIdx.x == 255) blockSums[blockIdx.x] = tmp[255];
}

__global__ void scan_sums(int* blockSums, int nb) {  // nb <= 512, single block of 512
    __shared__ int tmp[512];
    int v = (threadIdx.x < nb) ? blockSums[threadIdx.x] : 0;
    tmp[threadIdx.x] = v;
    __syncthreads();
    for (int off = 1; off < 512; off <<= 1) {
        int t = (threadIdx.x >= off) ? tmp[threadIdx.x - off] : 0;
        __syncthreads();
        if (threadIdx.x >= off) tmp[threadIdx.x] += t;
        __syncthreads();
    }
    if (threadIdx.x < nb) blockSums[threadIdx.x] = tmp[threadIdx.x] - v;  // exclusive
}

__global__ void add_offsets(int* __restrict__ excl, const int* __restrict__ blockSums, int n) {
    int i = blockIdx.x * 256 + threadIdx.x;
    if (i < n) excl[i] += blockSums[blockIdx.x];
}

__global__ void copy_cursor(const int* __restrict__ row_ptr, int* __restrict__ cursor, int n) {
    int i = blockIdx.x * blockDim.x + threadIdx.x;
    if (i < n) cursor[i] = row_ptr[i];
}

// ---------------- CSR fill: ssrc sorted by dst ----------------
__global__ void fill_csr(const void* edges, const int* __restrict__ flag,
                         int* cursor, int* __restrict__ ssrc, int E) {
    int e = blockIdx.x * blockDim.x + threadIdx.x;
    if (e >= E) return;
    int f = *flag;
    int s = load_edge(edges, e, f);
    int d = load_edge(edges, (size_t)E + e, f);
    int pos = atomicAdd(&cursor[d], 1);
    ssrc[pos] = s;
}

// ---------------- f32 tiled GEMM, 4x4 micro-tile (proven, used for layer 2) ----------------
template<int TM, int TN, int K, int KC, int THREADS>
__global__ __launch_bounds__(THREADS) void gemm_f32(
    const float* __restrict__ A, const float* __restrict__ B, float* __restrict__ C) {
    __shared__ float As[KC][TM + 1];
    __shared__ float Bs[KC][TN];
    const int tid = threadIdx.x;
    constexpr int TCN = TN / 4;
    const int tc = tid % TCN;
    const int tr = tid / TCN;
    const long long row0 = (long long)blockIdx.x * TM;
    float acc[4][4] = {};

    for (int k0 = 0; k0 < K; k0 += KC) {
        constexpr int A_LOADS = TM * KC / 4;
        for (int i = tid; i < A_LOADS; i += THREADS) {
            int r  = i / (KC / 4);
            int kq = i % (KC / 4);
            float4 a = *(const float4*)(A + (row0 + r) * K + k0 + kq * 4);
            As[kq * 4 + 0][r] = a.x;
            As[kq * 4 + 1][r] = a.y;
            As[kq * 4 + 2][r] = a.z;
            As[kq * 4 + 3][r] = a.w;
        }
        constexpr int B_LOADS = KC * TN / 4;
        for (int i = tid; i < B_LOADS; i += THREADS) {
            int kk = i / TCN;
            int cq = i % TCN;
            *(float4*)(&Bs[kk][cq * 4]) = *(const float4*)(B + (long long)(k0 + kk) * TN + cq * 4);
        }
        __syncthreads();
        #pragma unroll 16
        for (int kk = 0; kk < KC; ++kk) {
            const float a0 = As[kk][tr * 4 + 0];
            const float a1 = As[kk][tr * 4 + 1];
            const float a2 = As[kk][tr * 4 + 2];
            const float a3 = As[kk][tr * 4 + 3];
            const float4 b = *(const float4*)(&Bs[kk][tc * 4]);
            acc[0][0] = fmaf(a0, b.x, acc[0][0]); acc[0][1] = fmaf(a0, b.y, acc[0][1]);
            acc[0][2] = fmaf(a0, b.z, acc[0][2]); acc[0][3] = fmaf(a0, b.w, acc[0][3]);
            acc[1][0] = fmaf(a1, b.x, acc[1][0]); acc[1][1] = fmaf(a1, b.y, acc[1][1]);
            acc[1][2] = fmaf(a1, b.z, acc[1][2]); acc[1][3] = fmaf(a1, b.w, acc[1][3]);
            acc[2][0] = fmaf(a2, b.x, acc[2][0]); acc[2][1] = fmaf(a2, b.y, acc[2][1]);
            acc[2][2] = fmaf(a2, b.z, acc[2][2]); acc[2][3] = fmaf(a2, b.w, acc[2][3]);
            acc[3][0] = fmaf(a3, b.x, acc[3][0]); acc[3][1] = fmaf(a3, b.y, acc[3][1]);
            acc[3][2] = fmaf(a3, b.z, acc[3][2]); acc[3][3] = fmaf(a3, b.w, acc[3][3]);
        }
        __syncthreads();
    }
    #pragma unroll
    for (int i = 0; i < 4; ++i) {
        float4 v = make_float4(acc[i][0], acc[i][1], acc[i][2], acc[i][3]);
        *(float4*)(C + (row0 + tr * 4 + i) * TN + tc * 4) = v;
    }
}

// ---------------- f32 GEMM, 8x8 micro-tile (layer 1) ----------------
// TM=32, TN=128, THREADS=(TM/8)*(TN/8)=64. Micro-tile rows {tr*4+i, TM/2+tr*4+i},
// cols {tc*4+j, TN/2+tc*4+j} -> all LDS reads are aligned b128, <=2-way conflict.
template<int TM, int TN, int K, int KC, int THREADS>
__global__ __launch_bounds__(THREADS) void gemm_f32_88(
    const float* __restrict__ A, const float* __restrict__ B, float* __restrict__ C) {
    __shared__ float As[KC][TM + 4];
    __shared__ float Bs[KC][TN];
    const int tid = threadIdx.x;
    constexpr int TCN = TN / 8;          // 16
    const int tc = tid % TCN;
    const int tr = tid / TCN;            // 0..TM/8-1
    const long long row0 = (long long)blockIdx.x * TM;
    float acc[8][8] = {};

    for (int k0 = 0; k0 < K; k0 += KC) {
        constexpr int A_LOADS = TM * KC / 4;
        for (int i = tid; i < A_LOADS; i += THREADS) {
            int r  = i / (KC / 4);
            int kq = i % (KC / 4);
            float4 a = *(const float4*)(A + (row0 + r) * K + k0 + kq * 4);
            As[kq * 4 + 0][r] = a.x;
            As[kq * 4 + 1][r] = a.y;
            As[kq * 4 + 2][r] = a.z;
            As[kq * 4 + 3][r] = a.w;
        }
        constexpr int B_LOADS = KC * TN / 4;
        for (int i = tid; i < B_LOADS; i += THREADS) {
            int kk = i / (TN / 4);
            int cq = i % (TN / 4);
            *(float4*)(&Bs[kk][cq * 4]) = *(const float4*)(B + (long long)(k0 + kk) * TN + cq * 4);
        }
        __syncthreads();
        #pragma unroll
        for (int kk = 0; kk < KC; ++kk) {
            float4 a0 = *(const float4*)(&As[kk][tr * 4]);
            float4 a1 = *(const float4*)(&As[kk][tr * 4 + TM / 2]);
            float4 b0 = *(const float4*)(&Bs[kk][tc * 4]);
            float4 b1 = *(const float4*)(&Bs[kk][tc * 4 + TN / 2]);
            float ar[8] = {a0.x, a0.y, a0.z, a0.w, a1.x, a1.y, a1.z, a1.w};
            float br[8] = {b0.x, b0.y, b0.z, b0.w, b1.x, b1.y, b1.z, b1.w};
            #pragma unroll
            for (int i = 0; i < 8; ++i)
                #pragma unroll
                for (int j = 0; j < 8; ++j)
                    acc[i][j] = fmaf(ar[i], br[j], acc[i][j]);
        }
        __syncthreads();
    }
    #pragma unroll
    for (int i = 0; i < 8; ++i) {
        long long r = row0 + (i < 4 ? tr * 4 + i : TM / 2 + tr * 4 + (i - 4));
        float4 v0 = make_float4(acc[i][0], acc[i][1], acc[i][2], acc[i][3]);
        float4 v1 = make_float4(acc[i][4], acc[i][5], acc[i][6], acc[i][7]);
        *(float4*)(C + r * TN + tc * 4) = v0;
        *(float4*)(C + r * TN + TN / 2 + tc * 4) = v1;
    }
}

// ---------------- CSR gather: out[i] = b + h[i]*dis[i]^2 + sum_j h[s_j]*dis[s_j]*dis[i] ----
// C channels; C/4 threads per node (float4 each); NPB nodes per 256-thread block.
template<int C, int NPB>
__global__ void gather_layer(const float* __restrict__ h, const int* __restrict__ row_ptr,
                             const int* __restrict__ counts, const int* __restrict__ ssrc,
                             const float* __restrict__ dis, const float* __restrict__ bias,
                             float* __restrict__ outp, int n) {
    constexpr int TPN = C / 4;
    const int local = threadIdx.x / TPN;
    const int lane  = threadIdx.x % TPN;
    const int i = blockIdx.x * NPB + local;
    if (i >= n) return;
    const float4* h4 = (const float4*)h;
    float di = dis[i];
    float4 acc = ((const float4*)bias)[lane];
    {
        float w = di * di;
        float4 hv = h4[(size_t)i * TPN + lane];
        acc.x += hv.x * w; acc.y += hv.y * w; acc.z += hv.z * w; acc.w += hv.w * w;
    }
    int start = row_ptr[i];
    int cnt   = counts[i];
    for (int j = 0; j < cnt; ++j) {
        int s = ssrc[start + j];
        float w = dis[s] * di;
        float4 hv = h4[(size_t)s * TPN + lane];
        acc.x += hv.x * w; acc.y += hv.y * w; acc.z += hv.z * w; acc.w += hv.w * w;
    }
    ((float4*)outp)[(size_t)i * TPN + lane] = acc;
}

extern "C" void kernel_launch(void* const* d_in, const int* in_sizes, int n_in,
                              void* d_out, int out_size, void* d_ws, size_t ws_size,
                              hipStream_t stream) {
    const float* x     = (const float*)d_in[0];
    const void*  edges = d_in[1];
    const float* W1    = (const float*)d_in[2];
    const float* b1    = (const float*)d_in[3];
    const float* W2    = (const float*)d_in[4];
    const float* b2    = (const float*)d_in[5];
    float* out = (float*)d_out;

    const int n = in_sizes[0] / IN_C;      // 100000
    const int E = in_sizes[1] / 2;         // 1600000
    const int nb = (n + 255) / 256;        // scan blocks (391)

    // ---- workspace carve-up (256B-aligned), ~110.7 MB ----
    char* ws = (char*)d_ws;
    size_t off = 0;
    auto alloc = [&](size_t bytes) { char* p = ws + off; off += (bytes + 255) & ~(size_t)255; return p; };
    int*   flag      = (int*)  alloc(4);
    int*   counts    = (int*)  alloc((size_t)n * 4);
    int*   row_ptr   = (int*)  alloc((size_t)n * 4);
    int*   cursor    = (int*)  alloc((size_t)n * 4);
    int*   blockSums = (int*)  alloc(512 * 4);
    float* dis       = (float*)alloc((size_t)n * 4);
    int*   ssrc      = (int*)  alloc((size_t)E * 4);
    float* h         = (float*)alloc((size_t)n * HID_C * 4);   // reused as h2
    float* agg       = (float*)alloc((size_t)n * HID_C * 4);

    // 1. edge dtype detect
    detect_kernel<<<1, 64, 0, stream>>>(edges, E, n, flag);

    // 2. degree (int) -> dis
    zero_counts<<<nb, 256, 0, stream>>>(counts, n);
    count_deg<<<(E + 255) / 256, 256, 0, stream>>>(edges, flag, counts, E);
    make_dis<<<nb, 256, 0, stream>>>(counts, dis, n);

    // 3. CSR: row_ptr = exclusive_scan(counts); fill ssrc sorted by dst
    scan_block<<<nb, 256, 0, stream>>>(counts, row_ptr, blockSums, n);
    scan_sums<<<1, 512, 0, stream>>>(blockSums, nb);
    add_offsets<<<nb, 256, 0, stream>>>(row_ptr, blockSums, n);
    copy_cursor<<<nb, 256, 0, stream>>>(row_ptr, cursor, n);
    fill_csr<<<(E + 255) / 256, 256, 0, stream>>>(edges, flag, cursor, ssrc, E);

    // 4. layer 1: h = x @ W1; agg = b1 + self + gather
    gemm_f32_88<32, HID_C, IN_C, 16, 64><<<n / 32, 64, 0, stream>>>(x, W1, h);
    gather_layer<HID_C, 8><<<(n + 7) / 8, 256, 0, stream>>>(h, row_ptr, counts, ssrc, dis, b1, agg, n);

    // 5. layer 2: h2 = agg @ W2; out = b2 + self + gather
    gemm_f32<32, OUT_C, HID_C, 64, 128><<<n / 32, 128, 0, stream>>>(agg, W2, h);
    gather_layer<OUT_C, 16><<<(n + 15) / 16, 256, 0, stream>>>(h, row_ptr, counts, ssrc, dis, b2, out, n);
}

// Round 3
// 517.020 us; speedup vs baseline: 2.5425x; 1.1514x over previous
//
#include <hip/hip_runtime.h>
#include <math.h>

#define IN_C  256
#define HID_C 128
#define OUT_C 64

// ---------------- edge dtype detection ----------------
// Reference creates int64 edge_index; harness docs say int32. Detect on
// device: if the first 64 values interpreted as int64 are all valid node
// ids, the buffer is int64 (int32 data would need every 2nd id == 0).
__global__ void detect_kernel(const void* edges, int E, int n_nodes, int* flag) {
    if (threadIdx.x == 0 && blockIdx.x == 0) {
        const long long* p = (const long long*)edges;
        int k = E < 64 ? E : 64;
        int is64 = 1;
        for (int i = 0; i < k; ++i) {
            long long v = p[i];
            if (v < 0 || v >= n_nodes) { is64 = 0; break; }
        }
        *flag = is64;
    }
}

__device__ __forceinline__ int load_edge(const void* edges, size_t idx, int is64) {
    return is64 ? (int)((const long long*)edges)[idx] : ((const int*)edges)[idx];
}

// ---------------- degree / norm ----------------
__global__ void zero_counts(int* counts, int n) {
    int i = blockIdx.x * blockDim.x + threadIdx.x;
    if (i < n) counts[i] = 0;
}

__global__ void count_deg(const void* edges, const int* __restrict__ flag, int* counts, int E) {
    int e = blockIdx.x * blockDim.x + threadIdx.x;
    if (e < E) atomicAdd(&counts[load_edge(edges, (size_t)E + e, *flag)], 1);
}

__global__ void make_dis(const int* __restrict__ counts, float* dis, int n) {
    int i = blockIdx.x * blockDim.x + threadIdx.x;
    if (i < n) dis[i] = rsqrtf((float)counts[i] + 1.0f);  // +1 self-loop, deg >= 1
}

// ---------------- exclusive scan (3 kernels) ----------------
__global__ void scan_block(const int* __restrict__ counts, int* __restrict__ excl,
                           int* __restrict__ blockSums, int n) {
    __shared__ int tmp[256];
    int i = blockIdx.x * 256 + threadIdx.x;
    int v = (i < n) ? counts[i] : 0;
    tmp[threadIdx.x] = v;
    __syncthreads();
    for (int off = 1; off < 256; off <<= 1) {
        int t = (threadIdx.x >= off) ? tmp[threadIdx.x - off] : 0;
        __syncthreads();
        if (threadIdx.x >= off) tmp[threadIdx.x] += t;
        __syncthreads();
    }
    if (i < n) excl[i] = tmp[threadIdx.x] - v;
    if (threadIdx.x == 255) blockSums[blockIdx.x] = tmp[255];
}

__global__ void scan_sums(int* blockSums, int nb) {  // nb <= 512, single block of 512
    __shared__ int tmp[512];
    int v = (threadIdx.x < nb) ? blockSums[threadIdx.x] : 0;
    tmp[threadIdx.x] = v;
    __syncthreads();
    for (int off = 1; off < 512; off <<= 1) {
        int t = (threadIdx.x >= off) ? tmp[threadIdx.x - off] : 0;
        __syncthreads();
        if (threadIdx.x >= off) tmp[threadIdx.x] += t;
        __syncthreads();
    }
    if (threadIdx.x < nb) blockSums[threadIdx.x] = tmp[threadIdx.x] - v;  // exclusive
}

__global__ void add_offsets(int* __restrict__ excl, const int* __restrict__ blockSums, int n) {
    int i = blockIdx.x * 256 + threadIdx.x;
    if (i < n) excl[i] += blockSums[blockIdx.x];
}

__global__ void copy_cursor(const int* __restrict__ row_ptr, int* __restrict__ cursor, int n) {
    int i = blockIdx.x * blockDim.x + threadIdx.x;
    if (i < n) cursor[i] = row_ptr[i];
}

// ---------------- CSR fill: ssrc sorted by dst ----------------
__global__ void fill_csr(const void* edges, const int* __restrict__ flag,
                         int* cursor, int* __restrict__ ssrc, int E) {
    int e = blockIdx.x * blockDim.x + threadIdx.x;
    if (e >= E) return;
    int f = *flag;
    int s = load_edge(edges, e, f);
    int d = load_edge(edges, (size_t)E + e, f);
    int pos = atomicAdd(&cursor[d], 1);
    ssrc[pos] = s;
}

// ---------------- f32 GEMM, 128x128 tile, 8x8 micro, epilogue *dis[row] ----------------
// THREADS=256 (4 waves). C[i][c] = (A@B)[i][c] * dis[i]. Guarded for M tail.
template<int TM, int TN, int K, int KC>
__global__ __launch_bounds__(256) void gemm_scaled_88(
    const float* __restrict__ A, const float* __restrict__ B,
    const float* __restrict__ dis, float* __restrict__ C, int M) {
    __shared__ float As[KC][TM + 4];
    __shared__ float Bs[KC][TN + 4];
    const int tid = threadIdx.x;
    constexpr int TCN = TN / 8;            // 16
    const int tc = tid % TCN;
    const int tr = tid / TCN;              // 0..15
    const long long row0 = (long long)blockIdx.x * TM;
    float acc[8][8] = {};

    for (int k0 = 0; k0 < K; k0 += KC) {
        constexpr int A_LOADS = TM * KC / 4;
        #pragma unroll
        for (int i = tid; i < A_LOADS; i += 256) {
            int r  = i / (KC / 4);
            int kq = i % (KC / 4);
            long long row = row0 + r;
            float4 a = make_float4(0.f, 0.f, 0.f, 0.f);
            if (row < M) a = *(const float4*)(A + row * K + k0 + kq * 4);
            As[kq * 4 + 0][r] = a.x;
            As[kq * 4 + 1][r] = a.y;
            As[kq * 4 + 2][r] = a.z;
            As[kq * 4 + 3][r] = a.w;
        }
        constexpr int B_LOADS = KC * TN / 4;
        #pragma unroll
        for (int i = tid; i < B_LOADS; i += 256) {
            int kk = i / (TN / 4);
            int cq = i % (TN / 4);
            *(float4*)(&Bs[kk][cq * 4]) = *(const float4*)(B + (long long)(k0 + kk) * TN + cq * 4);
        }
        __syncthreads();
        #pragma unroll 8
        for (int kk = 0; kk < KC; ++kk) {
            float4 a0 = *(const float4*)(&As[kk][tr * 4]);
            float4 a1 = *(const float4*)(&As[kk][tr * 4 + TM / 2]);
            float4 b0 = *(const float4*)(&Bs[kk][tc * 4]);
            float4 b1 = *(const float4*)(&Bs[kk][tc * 4 + TN / 2]);
            float ar[8] = {a0.x, a0.y, a0.z, a0.w, a1.x, a1.y, a1.z, a1.w};
            float br[8] = {b0.x, b0.y, b0.z, b0.w, b1.x, b1.y, b1.z, b1.w};
            #pragma unroll
            for (int i = 0; i < 8; ++i)
                #pragma unroll
                for (int j = 0; j < 8; ++j)
                    acc[i][j] = fmaf(ar[i], br[j], acc[i][j]);
        }
        __syncthreads();
    }
    #pragma unroll
    for (int i = 0; i < 8; ++i) {
        long long r = row0 + (i < 4 ? tr * 4 + i : TM / 2 + tr * 4 + (i - 4));
        if (r >= M) continue;
        float d = dis[r];
        float4 v0 = make_float4(acc[i][0] * d, acc[i][1] * d, acc[i][2] * d, acc[i][3] * d);
        float4 v1 = make_float4(acc[i][4] * d, acc[i][5] * d, acc[i][6] * d, acc[i][7] * d);
        *(float4*)(C + r * TN + tc * 4) = v0;
        *(float4*)(C + r * TN + TN / 2 + tc * 4) = v1;
    }
}

// ---------------- f32 GEMM, 128x64 tile, 4x8 micro, epilogue *dis[row] ----------------
template<int TM, int TN, int K, int KC>
__global__ __launch_bounds__(256) void gemm_scaled_48(
    const float* __restrict__ A, const float* __restrict__ B,
    const float* __restrict__ dis, float* __restrict__ C, int M) {
    __shared__ float As[KC][TM + 4];
    __shared__ float Bs[KC][TN + 4];
    const int tid = threadIdx.x;
    constexpr int TCN = TN / 8;            // 8
    const int tc = tid % TCN;
    const int tr = tid / TCN;              // 0..31
    const long long row0 = (long long)blockIdx.x * TM;
    float acc[4][8] = {};

    for (int k0 = 0; k0 < K; k0 += KC) {
        constexpr int A_LOADS = TM * KC / 4;
        #pragma unroll
        for (int i = tid; i < A_LOADS; i += 256) {
            int r  = i / (KC / 4);
            int kq = i % (KC / 4);
            long long row = row0 + r;
            float4 a = make_float4(0.f, 0.f, 0.f, 0.f);
            if (row < M) a = *(const float4*)(A + row * K + k0 + kq * 4);
            As[kq * 4 + 0][r] = a.x;
            As[kq * 4 + 1][r] = a.y;
            As[kq * 4 + 2][r] = a.z;
            As[kq * 4 + 3][r] = a.w;
        }
        constexpr int B_LOADS = KC * TN / 4;
        #pragma unroll
        for (int i = tid; i < B_LOADS; i += 256) {
            int kk = i / (TN / 4);
            int cq = i % (TN / 4);
            *(float4*)(&Bs[kk][cq * 4]) = *(const float4*)(B + (long long)(k0 + kk) * TN + cq * 4);
        }
        __syncthreads();
        #pragma unroll 8
        for (int kk = 0; kk < KC; ++kk) {
            float4 a0 = *(const float4*)(&As[kk][tr * 4]);
            float4 b0 = *(const float4*)(&Bs[kk][tc * 4]);
            float4 b1 = *(const float4*)(&Bs[kk][tc * 4 + TN / 2]);
            float ar[4] = {a0.x, a0.y, a0.z, a0.w};
            float br[8] = {b0.x, b0.y, b0.z, b0.w, b1.x, b1.y, b1.z, b1.w};
            #pragma unroll
            for (int i = 0; i < 4; ++i)
                #pragma unroll
                for (int j = 0; j < 8; ++j)
                    acc[i][j] = fmaf(ar[i], br[j], acc[i][j]);
        }
        __syncthreads();
    }
    #pragma unroll
    for (int i = 0; i < 4; ++i) {
        long long r = row0 + tr * 4 + i;
        if (r >= M) continue;
        float d = dis[r];
        float4 v0 = make_float4(acc[i][0] * d, acc[i][1] * d, acc[i][2] * d, acc[i][3] * d);
        float4 v1 = make_float4(acc[i][4] * d, acc[i][5] * d, acc[i][6] * d, acc[i][7] * d);
        *(float4*)(C + r * TN + tc * 4) = v0;
        *(float4*)(C + r * TN + TN / 2 + tc * 4) = v1;
    }
}

// ---------------- CSR gather on pre-scaled hs = h*dis ----------------
// out[i] = b + dis[i]*(hs[i] + sum_j hs[src_j]); inner loop is pure gather+add.
// C channels; C/4 threads per node; NPB nodes per 256-thread block. MLP-4 unroll.
template<int C, int NPB>
__global__ __launch_bounds__(256) void gather_layer(
    const float* __restrict__ hs, const int* __restrict__ row_ptr,
    const int* __restrict__ counts, const int* __restrict__ ssrc,
    const float* __restrict__ dis, const float* __restrict__ bias,
    float* __restrict__ outp, int n) {
    constexpr int TPN = C / 4;
    const int local = threadIdx.x / TPN;
    const int lane  = threadIdx.x % TPN;
    const int i = blockIdx.x * NPB + local;
    if (i >= n) return;
    const float4* h4 = (const float4*)hs;
    float di = dis[i];
    float4 acc = h4[(size_t)i * TPN + lane];   // self term (hs[i])
    const int start = row_ptr[i];
    const int cnt   = counts[i];
    const int* sp = ssrc + start;
    int j = 0;
    for (; j + 4 <= cnt; j += 4) {
        int s0 = sp[j], s1 = sp[j + 1], s2 = sp[j + 2], s3 = sp[j + 3];
        float4 v0 = h4[(size_t)s0 * TPN + lane];
        float4 v1 = h4[(size_t)s1 * TPN + lane];
        float4 v2 = h4[(size_t)s2 * TPN + lane];
        float4 v3 = h4[(size_t)s3 * TPN + lane];
        acc.x += (v0.x + v1.x) + (v2.x + v3.x);
        acc.y += (v0.y + v1.y) + (v2.y + v3.y);
        acc.z += (v0.z + v1.z) + (v2.z + v3.z);
        acc.w += (v0.w + v1.w) + (v2.w + v3.w);
    }
    for (; j < cnt; ++j) {
        int s = sp[j];
        float4 v = h4[(size_t)s * TPN + lane];
        acc.x += v.x; acc.y += v.y; acc.z += v.z; acc.w += v.w;
    }
    float4 bv = ((const float4*)bias)[lane];
    float4 o;
    o.x = bv.x + di * acc.x; o.y = bv.y + di * acc.y;
    o.z = bv.z + di * acc.z; o.w = bv.w + di * acc.w;
    ((float4*)outp)[(size_t)i * TPN + lane] = o;
}

extern "C" void kernel_launch(void* const* d_in, const int* in_sizes, int n_in,
                              void* d_out, int out_size, void* d_ws, size_t ws_size,
                              hipStream_t stream) {
    const float* x     = (const float*)d_in[0];
    const void*  edges = d_in[1];
    const float* W1    = (const float*)d_in[2];
    const float* b1    = (const float*)d_in[3];
    const float* W2    = (const float*)d_in[4];
    const float* b2    = (const float*)d_in[5];
    float* out = (float*)d_out;

    const int n = in_sizes[0] / IN_C;      // 100000
    const int E = in_sizes[1] / 2;         // 1600000
    const int nb = (n + 255) / 256;        // scan blocks (391)

    // ---- workspace carve-up (256B-aligned), ~110.7 MB ----
    char* ws = (char*)d_ws;
    size_t off = 0;
    auto alloc = [&](size_t bytes) { char* p = ws + off; off += (bytes + 255) & ~(size_t)255; return p; };
    int*   flag      = (int*)  alloc(4);
    int*   counts    = (int*)  alloc((size_t)n * 4);
    int*   row_ptr   = (int*)  alloc((size_t)n * 4);
    int*   cursor    = (int*)  alloc((size_t)n * 4);
    int*   blockSums = (int*)  alloc(512 * 4);
    float* dis       = (float*)alloc((size_t)n * 4);
    int*   ssrc      = (int*)  alloc((size_t)E * 4);
    float* hs        = (float*)alloc((size_t)n * HID_C * 4);   // scaled h; reused as hs2
    float* agg       = (float*)alloc((size_t)n * HID_C * 4);

    // 1. edge dtype detect
    detect_kernel<<<1, 64, 0, stream>>>(edges, E, n, flag);

    // 2. degree (int) -> dis
    zero_counts<<<nb, 256, 0, stream>>>(counts, n);
    count_deg<<<(E + 255) / 256, 256, 0, stream>>>(edges, flag, counts, E);
    make_dis<<<nb, 256, 0, stream>>>(counts, dis, n);

    // 3. CSR: row_ptr = exclusive_scan(counts); fill ssrc sorted by dst
    scan_block<<<nb, 256, 0, stream>>>(counts, row_ptr, blockSums, n);
    scan_sums<<<1, 512, 0, stream>>>(blockSums, nb);
    add_offsets<<<nb, 256, 0, stream>>>(row_ptr, blockSums, n);
    copy_cursor<<<nb, 256, 0, stream>>>(row_ptr, cursor, n);
    fill_csr<<<(E + 255) / 256, 256, 0, stream>>>(edges, flag, cursor, ssrc, E);

    // 4. layer 1: hs = (x @ W1) * dis; agg = b1 + dis*(self + gather)
    gemm_scaled_88<128, HID_C, IN_C, 32><<<(n + 127) / 128, 256, 0, stream>>>(x, W1, dis, hs, n);
    gather_layer<HID_C, 8><<<(n + 7) / 8, 256, 0, stream>>>(hs, row_ptr, counts, ssrc, dis, b1, agg, n);

    // 5. layer 2: hs2 = (agg @ W2) * dis; out = b2 + dis*(self + gather)
    gemm_scaled_48<128, OUT_C, HID_C, 32><<<(n + 127) / 128, 256, 0, stream>>>(agg, W2, dis, hs, n);
    gather_layer<OUT_C, 16><<<(n + 15) / 16, 256, 0, stream>>>(hs, row_ptr, counts, ssrc, dis, b2, out, n);
}

// Round 4
// 462.990 us; speedup vs baseline: 2.8392x; 1.1167x over previous
//
#include <hip/hip_runtime.h>
#include <math.h>

#define IN_C  256
#define HID_C 128
#define OUT_C 64

// ---------------- edge dtype detection ----------------
// Reference creates int64 edge_index; harness docs say int32. Detect on
// device: if the first 64 values interpreted as int64 are all valid node
// ids, the buffer is int64 (int32 data would need every 2nd id == 0).
__global__ void detect_kernel(const void* edges, int E, int n_nodes, int* flag) {
    if (threadIdx.x == 0 && blockIdx.x == 0) {
        const long long* p = (const long long*)edges;
        int k = E < 64 ? E : 64;
        int is64 = 1;
        for (int i = 0; i < k; ++i) {
            long long v = p[i];
            if (v < 0 || v >= n_nodes) { is64 = 0; break; }
        }
        *flag = is64;
    }
}

__device__ __forceinline__ int load_edge(const void* edges, size_t idx, int is64) {
    return is64 ? (int)((const long long*)edges)[idx] : ((const int*)edges)[idx];
}

// ---------------- degree count ----------------
__global__ void zero_counts(int* counts, int n) {
    int i = blockIdx.x * blockDim.x + threadIdx.x;
    if (i < n) counts[i] = 0;
}

__global__ void count_deg(const void* edges, const int* __restrict__ flag, int* counts, int E) {
    const int f = *flag;
    int t = blockIdx.x * blockDim.x + threadIdx.x;
    int stride = gridDim.x * blockDim.x;
    for (int e = t; e < E; e += stride)
        atomicAdd(&counts[load_edge(edges, (size_t)E + e, f)], 1);
}

// ---------------- scan (block phase) + dis = rsqrt(deg+1) fused ----------------
__global__ void scan_block_dis(const int* __restrict__ counts, int* __restrict__ excl,
                               int* __restrict__ blockSums, float* __restrict__ dis, int n) {
    __shared__ int tmp[256];
    int i = blockIdx.x * 256 + threadIdx.x;
    int v = (i < n) ? counts[i] : 0;
    if (i < n) dis[i] = rsqrtf((float)v + 1.0f);   // +1 self-loop
    tmp[threadIdx.x] = v;
    __syncthreads();
    for (int off = 1; off < 256; off <<= 1) {
        int t = (threadIdx.x >= off) ? tmp[threadIdx.x - off] : 0;
        __syncthreads();
        if (threadIdx.x >= off) tmp[threadIdx.x] += t;
        __syncthreads();
    }
    if (i < n) excl[i] = tmp[threadIdx.x] - v;
    if (threadIdx.x == 255) blockSums[blockIdx.x] = tmp[255];
}

__global__ void scan_sums(int* blockSums, int nb) {  // nb <= 512, single block of 512
    __shared__ int tmp[512];
    int v = (threadIdx.x < nb) ? blockSums[threadIdx.x] : 0;
    tmp[threadIdx.x] = v;
    __syncthreads();
    for (int off = 1; off < 512; off <<= 1) {
        int t = (threadIdx.x >= off) ? tmp[threadIdx.x - off] : 0;
        __syncthreads();
        if (threadIdx.x >= off) tmp[threadIdx.x] += t;
        __syncthreads();
    }
    if (threadIdx.x < nb) blockSums[threadIdx.x] = tmp[threadIdx.x] - v;  // exclusive
}

__global__ void add_offsets_cursor(int* __restrict__ excl, const int* __restrict__ blockSums,
                                   int* __restrict__ cursor, int n) {
    int i = blockIdx.x * 256 + threadIdx.x;
    if (i < n) {
        int v = excl[i] + blockSums[blockIdx.x];
        excl[i] = v;
        cursor[i] = v;
    }
}

// ---------------- FUSED: gemm1 (x@W1)*dis  ||  CSR fill ----------------
// Independent work overlapped in one kernel: GEMM blocks are VALU-bound,
// fill blocks are memory-latency-bound with idle VALU.
// Block mapping (G gemm blocks, F fill blocks, F >= G):
//   bid < 2G:  even -> gemm bid/2, odd -> fill (bid-1)/2
//   bid >= 2G: fill bid - G
// Fill: 1024 edges per block (256 thr x 4).
template<int TM, int TN, int K, int KC>
__global__ __launch_bounds__(256) void fused_gemm_fill(
    const float* __restrict__ A, const float* __restrict__ B,
    const float* __restrict__ dis, float* __restrict__ C, int M, int G,
    const void* edges, const int* __restrict__ flag,
    int* cursor, int* __restrict__ ssrc, int E) {
    __shared__ float As[KC][TM + 4];
    __shared__ float Bs[KC][TN + 4];
    const int bid = blockIdx.x;
    const bool is_gemm = (bid < 2 * G) && ((bid & 1) == 0);

    if (!is_gemm) {
        const int fb = (bid < 2 * G) ? (bid >> 1) : (bid - G);
        const int f = *flag;
        const size_t base = (size_t)fb * 1024 + threadIdx.x;
        int s[4], d[4];
        #pragma unroll
        for (int k = 0; k < 4; ++k) {
            size_t e = base + k * 256;
            if (e < (size_t)E) {
                s[k] = load_edge(edges, e, f);
                d[k] = load_edge(edges, (size_t)E + e, f);
            } else d[k] = -1;
        }
        #pragma unroll
        for (int k = 0; k < 4; ++k) {
            if (d[k] >= 0) {
                int pos = atomicAdd(&cursor[d[k]], 1);
                ssrc[pos] = s[k];
            }
        }
        return;
    }

    const int g = bid >> 1;
    const int tid = threadIdx.x;
    constexpr int TCN = TN / 8;            // 16
    const int tc = tid % TCN;
    const int tr = tid / TCN;              // 0..15
    const long long row0 = (long long)g * TM;
    float acc[8][8] = {};

    for (int k0 = 0; k0 < K; k0 += KC) {
        constexpr int A_LOADS = TM * KC / 4;
        #pragma unroll
        for (int i = tid; i < A_LOADS; i += 256) {
            int r  = i / (KC / 4);
            int kq = i % (KC / 4);
            long long row = row0 + r;
            float4 a = make_float4(0.f, 0.f, 0.f, 0.f);
            if (row < M) a = *(const float4*)(A + row * K + k0 + kq * 4);
            As[kq * 4 + 0][r] = a.x;
            As[kq * 4 + 1][r] = a.y;
            As[kq * 4 + 2][r] = a.z;
            As[kq * 4 + 3][r] = a.w;
        }
        constexpr int B_LOADS = KC * TN / 4;
        #pragma unroll
        for (int i = tid; i < B_LOADS; i += 256) {
            int kk = i / (TN / 4);
            int cq = i % (TN / 4);
            *(float4*)(&Bs[kk][cq * 4]) = *(const float4*)(B + (long long)(k0 + kk) * TN + cq * 4);
        }
        __syncthreads();
        #pragma unroll 8
        for (int kk = 0; kk < KC; ++kk) {
            float4 a0 = *(const float4*)(&As[kk][tr * 4]);
            float4 a1 = *(const float4*)(&As[kk][tr * 4 + TM / 2]);
            float4 b0 = *(const float4*)(&Bs[kk][tc * 4]);
            float4 b1 = *(const float4*)(&Bs[kk][tc * 4 + TN / 2]);
            float ar[8] = {a0.x, a0.y, a0.z, a0.w, a1.x, a1.y, a1.z, a1.w};
            float br[8] = {b0.x, b0.y, b0.z, b0.w, b1.x, b1.y, b1.z, b1.w};
            #pragma unroll
            for (int i = 0; i < 8; ++i)
                #pragma unroll
                for (int j = 0; j < 8; ++j)
                    acc[i][j] = fmaf(ar[i], br[j], acc[i][j]);
        }
        __syncthreads();
    }
    #pragma unroll
    for (int i = 0; i < 8; ++i) {
        long long r = row0 + (i < 4 ? tr * 4 + i : TM / 2 + tr * 4 + (i - 4));
        if (r >= M) continue;
        float d = dis[r];
        float4 v0 = make_float4(acc[i][0] * d, acc[i][1] * d, acc[i][2] * d, acc[i][3] * d);
        float4 v1 = make_float4(acc[i][4] * d, acc[i][5] * d, acc[i][6] * d, acc[i][7] * d);
        *(float4*)(C + r * TN + tc * 4) = v0;
        *(float4*)(C + r * TN + TN / 2 + tc * 4) = v1;
    }
}

// ---------------- f32 GEMM, 128x64 tile, 4x8 micro, epilogue *dis[row] ----------------
template<int TM, int TN, int K, int KC>
__global__ __launch_bounds__(256) void gemm_scaled_48(
    const float* __restrict__ A, const float* __restrict__ B,
    const float* __restrict__ dis, float* __restrict__ C, int M) {
    __shared__ float As[KC][TM + 4];
    __shared__ float Bs[KC][TN + 4];
    const int tid = threadIdx.x;
    constexpr int TCN = TN / 8;            // 8
    const int tc = tid % TCN;
    const int tr = tid / TCN;              // 0..31
    const long long row0 = (long long)blockIdx.x * TM;
    float acc[4][8] = {};

    for (int k0 = 0; k0 < K; k0 += KC) {
        constexpr int A_LOADS = TM * KC / 4;
        #pragma unroll
        for (int i = tid; i < A_LOADS; i += 256) {
            int r  = i / (KC / 4);
            int kq = i % (KC / 4);
            long long row = row0 + r;
            float4 a = make_float4(0.f, 0.f, 0.f, 0.f);
            if (row < M) a = *(const float4*)(A + row * K + k0 + kq * 4);
            As[kq * 4 + 0][r] = a.x;
            As[kq * 4 + 1][r] = a.y;
            As[kq * 4 + 2][r] = a.z;
            As[kq * 4 + 3][r] = a.w;
        }
        constexpr int B_LOADS = KC * TN / 4;
        #pragma unroll
        for (int i = tid; i < B_LOADS; i += 256) {
            int kk = i / (TN / 4);
            int cq = i % (TN / 4);
            *(float4*)(&Bs[kk][cq * 4]) = *(const float4*)(B + (long long)(k0 + kk) * TN + cq * 4);
        }
        __syncthreads();
        #pragma unroll 8
        for (int kk = 0; kk < KC; ++kk) {
            float4 a0 = *(const float4*)(&As[kk][tr * 4]);
            float4 b0 = *(const float4*)(&Bs[kk][tc * 4]);
            float4 b1 = *(const float4*)(&Bs[kk][tc * 4 + TN / 2]);
            float ar[4] = {a0.x, a0.y, a0.z, a0.w};
            float br[8] = {b0.x, b0.y, b0.z, b0.w, b1.x, b1.y, b1.z, b1.w};
            #pragma unroll
            for (int i = 0; i < 4; ++i)
                #pragma unroll
                for (int j = 0; j < 8; ++j)
                    acc[i][j] = fmaf(ar[i], br[j], acc[i][j]);
        }
        __syncthreads();
    }
    #pragma unroll
    for (int i = 0; i < 4; ++i) {
        long long r = row0 + tr * 4 + i;
        if (r >= M) continue;
        float d = dis[r];
        float4 v0 = make_float4(acc[i][0] * d, acc[i][1] * d, acc[i][2] * d, acc[i][3] * d);
        float4 v1 = make_float4(acc[i][4] * d, acc[i][5] * d, acc[i][6] * d, acc[i][7] * d);
        *(float4*)(C + r * TN + tc * 4) = v0;
        *(float4*)(C + r * TN + TN / 2 + tc * 4) = v1;
    }
}

// ---------------- CSR gather on pre-scaled hs = h*dis ----------------
// out[i] = b + dis[i]*(hs[i] + sum_j hs[src_j]); inner loop is pure gather+add.
template<int C, int NPB>
__global__ __launch_bounds__(256) void gather_layer(
    const float* __restrict__ hs, const int* __restrict__ row_ptr,
    const int* __restrict__ counts, const int* __restrict__ ssrc,
    const float* __restrict__ dis, const float* __restrict__ bias,
    float* __restrict__ outp, int n) {
    constexpr int TPN = C / 4;
    const int local = threadIdx.x / TPN;
    const int lane  = threadIdx.x % TPN;
    const int i = blockIdx.x * NPB + local;
    if (i >= n) return;
    const float4* h4 = (const float4*)hs;
    float di = dis[i];
    float4 acc = h4[(size_t)i * TPN + lane];   // self term (hs[i])
    const int start = row_ptr[i];
    const int cnt   = counts[i];
    const int* sp = ssrc + start;
    int j = 0;
    for (; j + 4 <= cnt; j += 4) {
        int s0 = sp[j], s1 = sp[j + 1], s2 = sp[j + 2], s3 = sp[j + 3];
        float4 v0 = h4[(size_t)s0 * TPN + lane];
        float4 v1 = h4[(size_t)s1 * TPN + lane];
        float4 v2 = h4[(size_t)s2 * TPN + lane];
        float4 v3 = h4[(size_t)s3 * TPN + lane];
        acc.x += (v0.x + v1.x) + (v2.x + v3.x);
        acc.y += (v0.y + v1.y) + (v2.y + v3.y);
        acc.z += (v0.z + v1.z) + (v2.z + v3.z);
        acc.w += (v0.w + v1.w) + (v2.w + v3.w);
    }
    for (; j < cnt; ++j) {
        int s = sp[j];
        float4 v = h4[(size_t)s * TPN + lane];
        acc.x += v.x; acc.y += v.y; acc.z += v.z; acc.w += v.w;
    }
    float4 bv = ((const float4*)bias)[lane];
    float4 o;
    o.x = bv.x + di * acc.x; o.y = bv.y + di * acc.y;
    o.z = bv.z + di * acc.z; o.w = bv.w + di * acc.w;
    ((float4*)outp)[(size_t)i * TPN + lane] = o;
}

extern "C" void kernel_launch(void* const* d_in, const int* in_sizes, int n_in,
                              void* d_out, int out_size, void* d_ws, size_t ws_size,
                              hipStream_t stream) {
    const float* x     = (const float*)d_in[0];
    const void*  edges = d_in[1];
    const float* W1    = (const float*)d_in[2];
    const float* b1    = (const float*)d_in[3];
    const float* W2    = (const float*)d_in[4];
    const float* b2    = (const float*)d_in[5];
    float* out = (float*)d_out;

    const int n = in_sizes[0] / IN_C;      // 100000
    const int E = in_sizes[1] / 2;         // 1600000
    const int nb = (n + 255) / 256;        // scan blocks (391)

    // ---- workspace carve-up (256B-aligned), ~110.7 MB ----
    char* ws = (char*)d_ws;
    size_t off = 0;
    auto alloc = [&](size_t bytes) { char* p = ws + off; off += (bytes + 255) & ~(size_t)255; return p; };
    int*   flag      = (int*)  alloc(4);
    int*   counts    = (int*)  alloc((size_t)n * 4);
    int*   row_ptr   = (int*)  alloc((size_t)n * 4);
    int*   cursor    = (int*)  alloc((size_t)n * 4);
    int*   blockSums = (int*)  alloc(512 * 4);
    float* dis       = (float*)alloc((size_t)n * 4);
    int*   ssrc      = (int*)  alloc((size_t)E * 4);
    float* hs        = (float*)alloc((size_t)n * HID_C * 4);   // scaled h; reused as hs2
    float* agg       = (float*)alloc((size_t)n * HID_C * 4);

    // 1. edge dtype detect
    detect_kernel<<<1, 64, 0, stream>>>(edges, E, n, flag);

    // 2. degree (int) -> scan(+dis) -> cursor
    zero_counts<<<nb, 256, 0, stream>>>(counts, n);
    count_deg<<<(E / 4 + 255) / 256, 256, 0, stream>>>(edges, flag, counts, E);
    scan_block_dis<<<nb, 256, 0, stream>>>(counts, row_ptr, blockSums, dis, n);
    scan_sums<<<1, 512, 0, stream>>>(blockSums, nb);
    add_offsets_cursor<<<nb, 256, 0, stream>>>(row_ptr, blockSums, cursor, n);

    // 3. FUSED: layer-1 GEMM (hs = (x@W1)*dis) overlapped with CSR fill
    const int G = (n + 127) / 128;                 // 782 gemm blocks
    const int F = (E + 1023) / 1024;               // 1563 fill blocks (F >= G)
    fused_gemm_fill<128, HID_C, IN_C, 32><<<G + F, 256, 0, stream>>>(
        x, W1, dis, hs, n, G, edges, flag, cursor, ssrc, E);

    // 4. layer 1 aggregate: agg = b1 + dis*(self + gather)
    gather_layer<HID_C, 8><<<(n + 7) / 8, 256, 0, stream>>>(hs, row_ptr, counts, ssrc, dis, b1, agg, n);

    // 5. layer 2: hs2 = (agg @ W2) * dis; out = b2 + dis*(self + gather)
    gemm_scaled_48<128, OUT_C, HID_C, 32><<<(n + 127) / 128, 256, 0, stream>>>(agg, W2, dis, hs, n);
    gather_layer<OUT_C, 16><<<(n + 15) / 16, 256, 0, stream>>>(hs, row_ptr, counts, ssrc, dis, b2, out, n);
}